// Round 7
// baseline (138.563 us; speedup 1.0000x reference)
//
#include <hip/hip_runtime.h>
#include <stdint.h>

// Fused dynamic-filter network op, bf16 MFMA implicit-GEMM, pipelined.
//   filt[n,oc,h,w] = bc[oc] + sum_{ic,kh,kw} gt_zpad[n,ic,h+kh-1,w+kw-1]*Wc[oc,ic,kh,kw]
//   out[n,c,h,w]   = sum_{k=kh*3+kw} filt[n,c*9+k,h,w] * gr_reppad[n,c,h+kh-1,w+kw-1]
// N=8, C=64, H=W=128, OC=576. filt (302 MB) never materialized.
//
// ws layout:
//   [0, 663552)          Wc bf16, 36 blocks of [144 oc][64 ic], XOR-swizzled,
//                        oc rows PERMUTED: tile row r holds oc (r&15)*9 + (r>>4)
//   [663552, 680192)     16640 B of zeros (OOB row source for conv zero-pad in h)
//   [680192, 17719552)   gt bf16 row-blocks [n][y]: [130 r=w+1][64 ic], UNSWIZZLED
//                        (read directly from global now), r=0/129 zero (w-pad)
//
// R16 vs R10 (R12-R15: all reorder-at-source attempts landed 88-97us; the
// pipes serialize structurally): A LEAVES LDS ENTIRELY.
//  - A fragments load straight from global into VGPRs (SGPR row base + one
//    VGPR lane offset + imm). Per wave A is ~9KB re-read across taps ->
//    L1-resident; L2 demand ~15 B/cy/CU (R11's B-direct failure needed 104).
//    Prefetch one kk-phase ahead (ar0/ar1 ping-pong, ~1400cy slack).
//  - LDS reads drop 1872->1296/block; A staging (writes + 15 gload_lds/wave)
//    deleted; prep_gt unswizzled.
//  - Freed LDS (83KB) -> ALL 8 B tap-buffers resident (147KB): taps 1-7 run
//    with ZERO barriers (~20k cy free wave drift -> natural anti-phasing of
//    the 2 waves/SIMD; R13's goal without code duplication/spills).
//  - 3 barriers total: [vmcnt(4)+bar] post-prologue (B0-7 staged, A-tap0 in
//    flight), [raw bar] post-TAP0 (recycle buf0 for B8), [vmcnt(4)+bar]
//    pre-TAP8 (B8 landed; tap8's A prefetch stays in flight).
// B path, accumulation order, and register epilogue identical to R10.

typedef short bf16x8 __attribute__((ext_vector_type(8)));
typedef float f32x4 __attribute__((ext_vector_type(4)));

#define ROWBLK_B 16640
#define BTAP_B   18432
#define ZERO_OFF 663552
#define GTB_OFF  (ZERO_OFF + ROWBLK_B)

__device__ __forceinline__ uint32_t f2bf(float f) {
  uint32_t x = __float_as_uint(f);
  return (x + 0x7FFFu + ((x >> 16) & 1u)) >> 16;   // RNE
}

__device__ __forceinline__ void gload_lds16(const void* g, void* l) {
  __builtin_amdgcn_global_load_lds(
      (const __attribute__((address_space(1))) void*)g,
      (__attribute__((address_space(3))) void*)l, 16, 0, 0);
}

// ---- prep 1: Wc [576][64][3][3] f32 -> ws bf16 [tap*4+octile][144][64], pre-swizzled.
// Tile row r holds original oc = octile*144 + (r&15)*9 + (r>>4)  (pi permutation:
// D-row nf*16 + l4*4+q  ->  channel l4*4+q, dyn-tap nf).
__global__ void prep_wc(const float* __restrict__ Wc, uint8_t* __restrict__ ws) {
  int ch = blockIdx.x * 256 + threadIdx.x;   // 41472 x 16B chunks, exact
  int tb = ch / 1152;                        // tap*4 + octile
  int cw = ch - tb * 1152;
  int tap = tb >> 2, octile = tb & 3;
  int row = cw >> 3, sl = cw & 7;
  int slot = sl ^ (row & 7);                 // pre-apply read-side XOR swizzle
  int ic0 = slot * 8;
  int oc = octile * 144 + (row & 15) * 9 + (row >> 4);   // pi permutation
  uint32_t p[4];
#pragma unroll
  for (int e = 0; e < 4; ++e) {
    uint32_t lo = f2bf(Wc[(oc * 64 + ic0 + 2 * e) * 9 + tap]);
    uint32_t hi = f2bf(Wc[(oc * 64 + ic0 + 2 * e + 1) * 9 + tap]);
    p[e] = lo | (hi << 16);
  }
  uint4 u; u.x = p[0]; u.y = p[1]; u.z = p[2]; u.w = p[3];
  *(uint4*)(ws + (size_t)tb * BTAP_B + (size_t)cw * 16) = u;
}

// ---- prep 2: gt [8][64][128][128] f32 -> ws bf16 row-blocks, UNSWIZZLED, padded
// (A is now read directly from global; linear [r][ic] layout, r=w+1, zero rims)
__global__ void prep_gt(const float* __restrict__ gt, uint8_t* __restrict__ ws) {
  int b = blockIdx.x;
  if (b == 1024) {  // zero block for out-of-image rows
    uint4 z; z.x = z.y = z.z = z.w = 0;
    for (int i = threadIdx.x; i < 1040; i += 256)
      *(uint4*)(ws + ZERO_OFF + (size_t)i * 16) = z;
    return;
  }
  int n = b >> 7, y = b & 127;
  uint8_t* base = ws + GTB_OFF + (size_t)b * ROWBLK_B;
  for (int i = threadIdx.x; i < 1040; i += 256) {   // 1040 x 16B chunks per row-block
    int r = i >> 3, sl = i & 7;
    uint4 u; u.x = u.y = u.z = u.w = 0;
    if (r >= 1 && r <= 128) {
      int w = r - 1, ic0 = sl * 8;
      uint32_t p[4];
#pragma unroll
      for (int e = 0; e < 4; ++e) {
        uint32_t lo = f2bf(gt[((n * 64 + ic0 + 2 * e) * 128 + y) * 128 + w]);
        uint32_t hi = f2bf(gt[((n * 64 + ic0 + 2 * e + 1) * 128 + y) * 128 + w]);
        p[e] = lo | (hi << 16);
      }
      u.x = p[0]; u.y = p[1]; u.z = p[2]; u.w = p[3];
    }
    *(uint4*)(base + (size_t)i * 16) = u;
  }
}

// ---- main: per block M=512 pixels (4 rows x 128 w) x N=144 oc, K=576
__global__ __launch_bounds__(512, 2) void dfn_mfma(
    const float* __restrict__ gr, const float* __restrict__ bc,
    const uint8_t* __restrict__ ws, float* __restrict__ out) {
  __shared__ uint8_t smem[147456];           // B only: 8 tap-buffers x 18432
  const int tid = threadIdx.x;
  const int lane = tid & 63;
  const int wv = tid >> 6;
  const int l15 = lane & 15;
  const int l4 = lane >> 4;
  // XCD-coscheduling decode: bits[2:0]=nh_low, bits[4:3]=octile, bits[9:5]=nh_high.
  const int bid = blockIdx.x;
  const int octile = (bid >> 3) & 3;
  const int nh = (bid & 7) | ((bid >> 5) << 3);
  const int n = nh >> 5;
  const int h0 = (nh & 31) * 4;
  const int arow = wv >> 1;                  // wave's image row within block tile

  // B ds_read offsets (XOR-swizzled LDS image, unchanged)
  int bo[2];
#pragma unroll
  for (int kk = 0; kk < 2; ++kk)
    bo[kk] = l15 * 128 + ((kk * 64 + l4 * 16) ^ ((l15 & 7) << 4));
  // A global lane offset (UNSWIZZLED layout): + imm (DWP*128 + KK*64) per call
  const int avoff = l15 * 128 + l4 * 16;
  int mcol[4];                               // wave-uniform w-offsets
#pragma unroll
  for (int mf = 0; mf < 4; ++mf) mcol[mf] = ((wv * 4 + mf) & 7) * 2048;

  const uint8_t* gtb = ws + GTB_OFF;
  const uint8_t* zblk = ws + ZERO_OFF;

#define ISSUE_B(T, BUFI) do {                                                 \
    const uint8_t* bsrc_ = ws + (size_t)((T) * 4 + octile) * BTAP_B;          \
    uint8_t* bdst_ = smem + (size_t)(BUFI) * BTAP_B;                          \
    _Pragma("unroll")                                                         \
    for (int it = 0; it < 3; ++it) {                                          \
      int idx = it * 512 + tid;                                               \
      if (idx < 1152)                                                         \
        gload_lds16(bsrc_ + (size_t)idx * 16,                                 \
                    bdst_ + (size_t)(it * 512 + (tid & ~63)) * 16);           \
    }                                                                         \
  } while (0)

// A fragments: 4 global bf16x8 loads, wave-uniform base (zblk if row OOB)
#define ISSUE_A(ARR, DH, DWP, KK) do {                                        \
    int r_ = h0 + arow + (DH);                                                \
    const uint8_t* ab_ = (r_ >= 0 && r_ < 128)                                \
        ? (gtb + (size_t)(n * 128 + r_) * ROWBLK_B) : zblk;                   \
    _Pragma("unroll")                                                         \
    for (int mf = 0; mf < 4; ++mf)                                            \
      ARR[mf] = *(const bf16x8*)(ab_ + mcol[mf] + avoff                       \
                                 + (DWP) * 128 + (KK) * 64);                  \
  } while (0)

  f32x4 acc[4][9];
  bf16x8 ar0[4], ar1[4];                     // A frags, kk ping-pong

// one kk-phase: 9 B ds_reads (ring of 4) feeding 36 MFMA from ARR
#define PHASE(BUFI, KK, ARR) do {                                             \
    const uint8_t* baddr_ = smem + (size_t)(BUFI) * BTAP_B + bo[KK];          \
    bf16x8 bq[4];                                                             \
    _Pragma("unroll")                                                         \
    for (int p = 0; p < 4; ++p)                                               \
      bq[p] = *(const bf16x8*)(baddr_ + p * 2048);                            \
    __builtin_amdgcn_s_setprio(1);                                            \
    _Pragma("unroll")                                                         \
    for (int nf = 0; nf < 9; ++nf) {                                          \
      bf16x8 bcur_ = bq[nf & 3];                                              \
      if (nf + 4 < 9)                                                         \
        bq[nf & 3] = *(const bf16x8*)(baddr_ + (nf + 4) * 2048);              \
      _Pragma("unroll")                                                       \
      for (int mf = 0; mf < 4; ++mf)                                          \
        acc[mf][nf] = __builtin_amdgcn_mfma_f32_16x16x32_bf16(                \
            bcur_, ARR[mf], acc[mf][nf], 0, 0, 0);                            \
    }                                                                         \
    __builtin_amdgcn_s_setprio(0);                                            \
  } while (0)

// one tap with A prefetch: issue this tap's kk1 frags, compute kk0 (frags
// loaded one phase ago), issue NEXT tap's kk0 frags, compute kk1.
#define TAP_PF(BUFI, DH, DWP, NDH, NDWP, HASNEXT) do {                        \
    ISSUE_A(ar1, DH, DWP, 1);                                                 \
    PHASE(BUFI, 0, ar0);                                                      \
    if (HASNEXT) ISSUE_A(ar0, NDH, NDWP, 0);                                  \
    PHASE(BUFI, 1, ar1);                                                      \
  } while (0)

  // ---- prologue: stage ALL B taps 0..7 (24 loads/wave) + tap0 kk0 A frags
#pragma unroll
  for (int t = 0; t < 8; ++t) ISSUE_B(t, t);
  ISSUE_A(ar0, -1, 0, 0);

  // bias init overlaps staging: acc[mf][nf][q] = bc for
  // oc = octile*144 + (l4*4+q)*9 + nf  (channel l4*4+q, dyn-tap nf)
#pragma unroll
  for (int nf = 0; nf < 9; ++nf) {
#pragma unroll
    for (int q = 0; q < 4; ++q) {
      float bias = bc[octile * 144 + (l4 * 4 + q) * 9 + nf];
      acc[0][nf][q] = bias; acc[1][nf][q] = bias;
      acc[2][nf][q] = bias; acc[3][nf][q] = bias;
    }
  }
  // barrier #1: B0-7 visible (24 oldest retired); A-tap0 (4 newest) in flight
  asm volatile("s_waitcnt vmcnt(4)" ::: "memory");
  __builtin_amdgcn_s_barrier();

  // ---- tap 0, then recycle buf0 for tap 8
  TAP_PF(0, -1, 0, -1, 1, 1);
  __builtin_amdgcn_s_barrier();              // #2: all waves done reading buf0
  ISSUE_B(8, 0);

  // ---- taps 1..7: BARRIER-FREE (all B resident; A from global; waves drift)
  TAP_PF(1, -1, 1, -1, 2, 1);
  TAP_PF(2, -1, 2,  0, 0, 1);
  TAP_PF(3,  0, 0,  0, 1, 1);
  TAP_PF(4,  0, 1,  0, 2, 1);
  TAP_PF(5,  0, 2,  1, 0, 1);
  TAP_PF(6,  1, 0,  1, 1, 1);
  TAP_PF(7,  1, 1,  1, 2, 1);

  // barrier #3: B8 (3 oldest) landed; tap8 kk0 A-prefetch (4 newest) may fly
  asm volatile("s_waitcnt vmcnt(4)" ::: "memory");
  __builtin_amdgcn_s_barrier();
  TAP_PF(0,  1, 2,  0, 0, 0);               // tap 8 from buf0

  // ---- epilogue: register-direct. acc[mf][k][q] = filt(pixel(mf,l15),
  // channel l4*4+q, tap k). Pure VALU + global; no LDS.
  const float* grb = gr + (size_t)(n * 64 + octile * 16 + l4 * 4) * 16384;
  float* outb = out + (size_t)(n * 64 + octile * 16 + l4 * 4) * 16384;
#pragma unroll
  for (int mf = 0; mf < 4; ++mf) {
    int p = (wv * 4 + mf) * 16 + l15;         // pixel within 512-pixel tile
    int hrow = p >> 7, w = p & 127;
    int h = h0 + hrow;
    int off[3][3];                            // replicate-clamped, shared over q
#pragma unroll
    for (int i = 0; i < 3; ++i) {
      int yy = h + i - 1; yy = yy < 0 ? 0 : (yy > 127 ? 127 : yy);
#pragma unroll
      for (int j = 0; j < 3; ++j) {
        int xx = w + j - 1; xx = xx < 0 ? 0 : (xx > 127 ? 127 : xx);
        off[i][j] = yy * 128 + xx;
      }
    }
#pragma unroll
    for (int q = 0; q < 4; ++q) {
      const float* grc = grb + (size_t)q * 16384;
      float s = 0.f;
#pragma unroll
      for (int i = 0; i < 3; ++i)
#pragma unroll
        for (int j = 0; j < 3; ++j)
          s = fmaf(acc[mf][i * 3 + j][q], grc[off[i][j]], s);
      outb[(size_t)q * 16384 + h * 128 + w] = s;
    }
  }
}

extern "C" void kernel_launch(void* const* d_in, const int* in_sizes, int n_in,
                              void* d_out, int out_size, void* d_ws, size_t ws_size,
                              hipStream_t stream) {
  const float* gr = (const float*)d_in[0];
  const float* gt = (const float*)d_in[1];
  const float* Wc = (const float*)d_in[2];
  const float* bc = (const float*)d_in[3];
  uint8_t* ws = (uint8_t*)d_ws;
  float* out = (float*)d_out;

  prep_wc<<<162, 256, 0, stream>>>(Wc, ws);
  prep_gt<<<1025, 256, 0, stream>>>(gt, ws);
  dfn_mfma<<<1024, 512, 0, stream>>>(gr, bc, ws, out);
}